// Round 4
// baseline (325.735 us; speedup 1.0000x reference)
//
#include <hip/hip_runtime.h>

#define NH 16
#define DH 64
#define DM 1024
#define SEQ 2048
#define BATCH 4

typedef short s16x8 __attribute__((ext_vector_type(8)));
typedef float f32x4 __attribute__((ext_vector_type(4)));

__device__ __forceinline__ unsigned short f2bf(float f) {
  union { float f; unsigned int u; } v; v.f = f;
  unsigned int u = v.u;
  unsigned int r = (u + 0x7fffu + ((u >> 16) & 1u)) >> 16;
  return (unsigned short)r;
}

__device__ __forceinline__ unsigned int pkbf(float a, float b) {
#if __has_builtin(__builtin_amdgcn_cvt_pk_bf16_f32)
  typedef short v2s __attribute__((ext_vector_type(2)));
  v2s r = __builtin_amdgcn_cvt_pk_bf16_f32(a, b);
  union { v2s v; unsigned int u; } cv; cv.v = r;
  return cv.u;
#else
  return (unsigned int)f2bf(a) | ((unsigned int)f2bf(b) << 16);
#endif
}

__device__ __forceinline__ float fexp2(float x) {
#if __has_builtin(__builtin_amdgcn_exp2f)
  return __builtin_amdgcn_exp2f(x);
#else
  return exp2f(x);
#endif
}

__device__ __forceinline__ void gload_lds16(const void* g, void* l) {
  __builtin_amdgcn_global_load_lds(
      (const __attribute__((address_space(1))) unsigned int*)g,
      (__attribute__((address_space(3))) unsigned int*)l, 16, 0, 0);
}

// ---------------- fp32 -> bf16 convert (all tensors in one launch) ----------
__global__ void convert_all(const float* __restrict__ q, const float* __restrict__ kv,
                            const float* __restrict__ w0, const float* __restrict__ w1,
                            const float* __restrict__ w2, const float* __restrict__ w3,
                            unsigned short* __restrict__ oq, unsigned short* __restrict__ okv,
                            unsigned short* __restrict__ ow0, unsigned short* __restrict__ ow1,
                            unsigned short* __restrict__ ow2, unsigned short* __restrict__ ow3) {
  const int NQ4 = (BATCH * SEQ * DM) / 4;
  const int NW4 = (DM * DM) / 4;
  const int total = NQ4 * 2 + NW4 * 4;
  for (int i = blockIdx.x * blockDim.x + threadIdx.x; i < total;
       i += gridDim.x * blockDim.x) {
    const float* s; unsigned short* d; int off;
    if (i < NQ4)            { s = q;  d = oq;  off = i; }
    else if (i < 2 * NQ4)   { s = kv; d = okv; off = i - NQ4; }
    else {
      int j = i - 2 * NQ4; int wsel = j / NW4; off = j - wsel * NW4;
      s = (wsel == 0) ? w0 : (wsel == 1) ? w1 : (wsel == 2) ? w2 : w3;
      d = (wsel == 0) ? ow0 : (wsel == 1) ? ow1 : (wsel == 2) ? ow2 : ow3;
    }
    float4 v = *(const float4*)(s + (size_t)off * 4);
    ushort4 o;
    o.x = f2bf(v.x); o.y = f2bf(v.y); o.z = f2bf(v.z); o.w = f2bf(v.w);
    *(ushort4*)(d + (size_t)off * 4) = o;
  }
}

// ---------------- shared GEMM tile body (round-0 verified) ------------------
__device__ __forceinline__ void gemm_tile(const unsigned short* __restrict__ X,
                                          const unsigned short* __restrict__ Wt,
                                          unsigned short* As, unsigned short* Bs,
                                          int m0, int n0, f32x4 (*acc)[4]) {
  const int tid = threadIdx.x;
  const int wv_ = tid >> 6, lane = tid & 63;
  const int quad = lane >> 4, c = lane & 15;
  const int wm = (wv_ >> 1) * 64, wn = (wv_ & 1) * 64;
  const int srow = lane >> 3;
  const int scol = ((lane & 7) ^ srow) * 8;

  for (int kt = 0; kt < DM; kt += 64) {
#pragma unroll
    for (int i = 0; i < 4; ++i) {
      int reg = wv_ * 4 + i;
      gload_lds16(X + (size_t)(m0 + reg * 8 + srow) * DM + kt + scol,
                  (void*)(As + reg * 512));
      gload_lds16(Wt + (size_t)(n0 + reg * 8 + srow) * DM + kt + scol,
                  (void*)(Bs + reg * 512));
    }
    __syncthreads();
#pragma unroll
    for (int k2 = 0; k2 < 2; ++k2) {
      s16x8 a[4], b[4];
      int g = k2 * 4 + quad;
#pragma unroll
      for (int t = 0; t < 4; ++t)
        a[t] = *(const s16x8*)(As + (wm + t * 16 + c) * 64 + ((g ^ (c & 7)) * 8));
#pragma unroll
      for (int t = 0; t < 4; ++t)
        b[t] = *(const s16x8*)(Bs + (wn + t * 16 + c) * 64 + ((g ^ (c & 7)) * 8));
#pragma unroll
      for (int tm = 0; tm < 4; ++tm)
#pragma unroll
        for (int tn = 0; tn < 4; ++tn)
          acc[tm][tn] = __builtin_amdgcn_mfma_f32_16x16x32_bf16(
              a[tm], b[tn], acc[tm][tn], 0, 0, 0);
    }
    __syncthreads();
  }
}

// ---------------- fused QKV projection -------------------------------------
// flat grid 1536, XCD-chunked swizzle: XCD i gets logical blocks [i*192,(i+1)*192)
// -> each XCD touches only 3 B-panels (768KB, L2-resident) instead of 24 (6MB thrash).
__global__ __launch_bounds__(256)
void gemm_qkv(const unsigned short* __restrict__ Xq,
              const unsigned short* __restrict__ Xkv,
              const unsigned short* __restrict__ W0,
              const unsigned short* __restrict__ W1,
              const unsigned short* __restrict__ W2,
              const float* __restrict__ b0, const float* __restrict__ b1,
              const float* __restrict__ b2,
              unsigned short* __restrict__ OQ, unsigned short* __restrict__ OK_,
              unsigned short* __restrict__ OV) {
  __shared__ alignas(16) unsigned short As[128 * 64];
  __shared__ alignas(16) unsigned short Bs[128 * 64];
  const int wg = blockIdx.x;                    // 0..1535
  const int L = (wg & 7) * 192 + (wg >> 3);     // bijective (1536 % 8 == 0)
  const int m0 = (L & 63) * 128;
  const int yy = L >> 6;                        // 0..23
  const int ysel = yy >> 3;
  const int n0 = (yy & 7) * 128;
  const unsigned short* X = (ysel == 0) ? Xq : Xkv;
  const unsigned short* Wt = (ysel == 0) ? W0 : (ysel == 1) ? W1 : W2;
  const float* bias = (ysel == 0) ? b0 : (ysel == 1) ? b1 : b2;
  unsigned short* Out = (ysel == 0) ? OQ : (ysel == 1) ? OK_ : OV;
  // Q pre-scaled by log2(e)/sqrt(Dh) so attention can use exp2 directly
  const float scale = (ysel == 0) ? 0.1803368801f : 1.0f;

  f32x4 acc[4][4] = {};
  gemm_tile(X, Wt, As, Bs, m0, n0, acc);

  const int tid = threadIdx.x;
  const int wv_ = tid >> 6, lane = tid & 63;
  const int quad = lane >> 4, c = lane & 15;
  const int wm = (wv_ >> 1) * 64, wn = (wv_ & 1) * 64;
#pragma unroll
  for (int tm = 0; tm < 4; ++tm) {
#pragma unroll
    for (int tn = 0; tn < 4; ++tn) {
      int n = n0 + wn + tn * 16 + c;
      float bv = bias[n];
      int m_base = m0 + wm + tm * 16 + quad * 4;
      if (ysel == 2) {
        // V^T: p -> consecutive s; one 8B store
        int b_ = m_base >> 11, s_ = m_base & 2047, h_ = n >> 6, dh = n & 63;
        size_t idx = (((size_t)(b_ * NH + h_)) * DH + dh) * SEQ + s_;
        ushort4 o4;
        o4.x = f2bf(acc[tm][tn][0] + bv);
        o4.y = f2bf(acc[tm][tn][1] + bv);
        o4.z = f2bf(acc[tm][tn][2] + bv);
        o4.w = f2bf(acc[tm][tn][3] + bv);
        *(ushort4*)(&Out[idx]) = o4;
      } else {
#pragma unroll
        for (int p = 0; p < 4; ++p) {
          int m = m_base + p;
          float val = (acc[tm][tn][p] + bv) * scale;
          int b_ = m >> 11, s_ = m & 2047, h_ = n >> 6, dh = n & 63;
          size_t idx = (((size_t)(b_ * NH + h_)) * SEQ + s_) * DH + dh;
          Out[idx] = f2bf(val);
        }
      }
    }
  }
}

// ---------------- output projection (fp32 out) -----------------------------
__global__ __launch_bounds__(256)
void gemm_o(const unsigned short* __restrict__ X,
            const unsigned short* __restrict__ Wt,
            const float* __restrict__ bias, float* __restrict__ Out) {
  __shared__ alignas(16) unsigned short As[128 * 64];
  __shared__ alignas(16) unsigned short Bs[128 * 64];
  const int wg = blockIdx.x;                    // 0..511
  const int L = (wg & 7) * 64 + (wg >> 3);      // bijective (512 % 8 == 0)
  const int m0 = (L & 63) * 128;
  const int n0 = (L >> 6) * 128;
  f32x4 acc[4][4] = {};
  gemm_tile(X, Wt, As, Bs, m0, n0, acc);

  const int tid = threadIdx.x;
  const int wv_ = tid >> 6, lane = tid & 63;
  const int quad = lane >> 4, c = lane & 15;
  const int wm = (wv_ >> 1) * 64, wn = (wv_ & 1) * 64;
#pragma unroll
  for (int tm = 0; tm < 4; ++tm) {
#pragma unroll
    for (int tn = 0; tn < 4; ++tn) {
      int n = n0 + wn + tn * 16 + c;
      float bv = bias[n];
#pragma unroll
      for (int p = 0; p < 4; ++p) {
        int m = m0 + wm + tm * 16 + quad * 4 + p;
        Out[(size_t)m * DM + n] = acc[tm][tn][p] + bv;
      }
    }
  }
}

// ---------------- flash attention v6 ---------------------------------------
// v5 + three work-reductions:
//  (1) 8-wave blocks (512 thr) share ONE K/V staging -> staging per byte
//      halves (was per-4-wave-block); grid 64x4 = 256 = 1 block/CU.
//  (2) lsum via ones-MFMA: lacc[t] = mfma(ones, bp[t][jp], lacc[t]) replaces
//      64 VALU adds/tile + cross-quad shuffles (A=1 => all C rows = col-sum).
//  (3) XCD swizzle: all 4 q-blocks of a bh on one XCD (8 bh x 512KB = L2).
__global__ __launch_bounds__(512, 2)
void attn_kernel(const unsigned short* __restrict__ Qb,
                 const unsigned short* __restrict__ Kb,
                 const unsigned short* __restrict__ VTb,
                 unsigned short* __restrict__ Ob) {
  __shared__ alignas(16) unsigned short SM[18432];   // 36 KB

  const int tid = threadIdx.x, wv_ = tid >> 6, lane = tid & 63;
  const int quad = lane >> 4, c = lane & 15;
  const int wg = blockIdx.x;                  // 0..255
  const int bh = (wg & 7) + 8 * ((wg >> 3) >> 2);   // XCD-chunked: bh%8 = XCD
  const int qb = (wg >> 3) & 3;
  const unsigned short* Qp = Qb + (size_t)bh * SEQ * DH;
  const unsigned short* Kp = Kb + (size_t)bh * SEQ * DH;
  const unsigned short* Vp = VTb + (size_t)bh * DH * SEQ;
  const int wq0 = qb * 512 + wv_ * 64;

  // Q fragments (B-operand: lane c = q column) live in registers
  s16x8 aq[4][2];
#pragma unroll
  for (int t = 0; t < 4; ++t)
#pragma unroll
    for (int k2 = 0; k2 < 2; ++k2)
      aq[t][k2] = *(const s16x8*)(Qp + (size_t)(wq0 + t * 16 + c) * DH +
                                  k2 * 32 + quad * 8);

  f32x4 ot[4][4] = {};     // O^T accum: [dh-tile][q-tile], lane c = q col
  f32x4 lacc[4] = {};      // row-sum accumulator via ones-MFMA
  s16x8 ones;
  {
    union { s16x8 v; unsigned short u[8]; } o_;
#pragma unroll
    for (int j = 0; j < 8; ++j) o_.u[j] = 0x3F80;   // bf16 1.0
    ones = o_.v;
  }

  const int srow = lane >> 3;
  const int schunk = (lane & 7) ^ srow;

  // prologue: stage tile 0 -> buffer 0. 16 slabs (8 K + 8 V), 2 per wave.
  // K buffers at shorts 0 / 4096; V at 8192 / 12288.
#pragma unroll
  for (int i = 0; i < 2; ++i) {
    int slab = wv_ * 2 + i;
    if (slab < 8) {
      gload_lds16(Kp + (size_t)(slab * 8 + srow) * DH + schunk * 8,
                  (void*)(SM + slab * 512));
    } else {
      int s2 = slab - 8;
      gload_lds16(Vp + (size_t)(s2 * 8 + srow) * SEQ + schunk * 8,
                  (void*)(SM + 8192 + s2 * 512));
    }
  }

  for (int kt = 0; kt < SEQ; kt += 64) {
    const int cur = (kt >> 6) & 1;
    __syncthreads();   // drains this tile's loads; frees other buffer
    if (kt + 64 < SEQ) {
      const int nxt = cur ^ 1;
#pragma unroll
      for (int i = 0; i < 2; ++i) {
        int slab = wv_ * 2 + i;
        if (slab < 8) {
          gload_lds16(Kp + (size_t)(kt + 64 + slab * 8 + srow) * DH + schunk * 8,
                      (void*)(SM + nxt * 4096 + slab * 512));
        } else {
          int s2 = slab - 8;
          gload_lds16(Vp + (size_t)(s2 * 8 + srow) * SEQ + kt + 64 + schunk * 8,
                      (void*)(SM + 8192 + nxt * 4096 + s2 * 512));
        }
      }
    }
    const unsigned short* K_ = SM + cur * 4096;
    const unsigned short* V_ = SM + 8192 + cur * 4096;

    // S^T tiles: rows = keys (permuted), cols = q.  s[t][jp][h] elem p holds
    // score(key = jp*32 + quad*8 + h*4 + p  [via row perm], q = wq0+t*16+c)
    f32x4 s[4][2][2] = {};
#pragma unroll
    for (int k2 = 0; k2 < 2; ++k2) {
      s16x8 ak[2][2];
#pragma unroll
      for (int jp = 0; jp < 2; ++jp)
#pragma unroll
        for (int h = 0; h < 2; ++h) {
          int r = jp * 32 + ((c >> 2) << 3) + h * 4 + (c & 3);  // key row perm
          int g = k2 * 4 + quad;
          ak[jp][h] = *(const s16x8*)(K_ + r * 64 + ((g ^ (r & 7)) * 8));
        }
#pragma unroll
      for (int t = 0; t < 4; ++t)
#pragma unroll
        for (int jp = 0; jp < 2; ++jp)
#pragma unroll
          for (int h = 0; h < 2; ++h)
            s[t][jp][h] = __builtin_amdgcn_mfma_f32_16x16x32_bf16(
                ak[jp][h], aq[t][k2], s[t][jp][h], 0, 0, 0);
    }

    // exp2 + in-register pack to PV B-fragments (k order quad*8+0..7)
    s16x8 bp[4][2];
#pragma unroll
    for (int t = 0; t < 4; ++t)
#pragma unroll
      for (int jp = 0; jp < 2; ++jp) {
        float e00 = fexp2(s[t][jp][0][0]);
        float e01 = fexp2(s[t][jp][0][1]);
        float e02 = fexp2(s[t][jp][0][2]);
        float e03 = fexp2(s[t][jp][0][3]);
        float e10 = fexp2(s[t][jp][1][0]);
        float e11 = fexp2(s[t][jp][1][1]);
        float e12 = fexp2(s[t][jp][1][2]);
        float e13 = fexp2(s[t][jp][1][3]);
        union { s16x8 v; unsigned int u[4]; } pk;
        pk.u[0] = pkbf(e00, e01);
        pk.u[1] = pkbf(e02, e03);
        pk.u[2] = pkbf(e10, e11);
        pk.u[3] = pkbf(e12, e13);
        bp[t][jp] = pk.v;
        // row sum on the matrix pipe: every lane's lacc[t][*] accumulates
        // the full 32-key column sum for its q column c.
        lacc[t] = __builtin_amdgcn_mfma_f32_16x16x32_bf16(
            ones, bp[t][jp], lacc[t], 0, 0, 0);
      }

    // O^T += V^T . P^T   (A = V^T rows: lane c = dh row; B = bp)
#pragma unroll
    for (int jp = 0; jp < 2; ++jp)
#pragma unroll
      for (int dt = 0; dt < 4; ++dt) {
        int g = jp * 4 + quad;
        int r = dt * 16 + c;
        s16x8 av = *(const s16x8*)(V_ + r * 64 + ((g ^ (r & 7)) * 8));
#pragma unroll
        for (int t = 0; t < 4; ++t)
          ot[dt][t] = __builtin_amdgcn_mfma_f32_16x16x32_bf16(
              av, bp[t][jp], ot[dt][t], 0, 0, 0);
      }
  }

  __syncthreads();   // all tile compute done; reuse SM for O transpose

  // O^T (lane=q col, regs=dh) -> LDS (q rows x dh cols, stride 72) -> global,
  // in two wave-local half-passes (q rows wq0+half*32 .. +31).
  const int b_ = bh >> 4, h_ = bh & 15;
  const int ql = lane >> 1, hf = lane & 1;
  unsigned short* Lq = SM + wv_ * (32 * 72);
#pragma unroll
  for (int half = 0; half < 2; ++half) {
    if (half) asm volatile("s_waitcnt lgkmcnt(0)" ::: "memory");  // pass-0 reads done
#pragma unroll
    for (int t2 = 0; t2 < 2; ++t2) {
      int t = half * 2 + t2;
      float inv = 1.0f / lacc[t][0];
#pragma unroll
      for (int dt = 0; dt < 4; ++dt) {
        unsigned int w01 = pkbf(ot[dt][t][0] * inv, ot[dt][t][1] * inv);
        unsigned int w23 = pkbf(ot[dt][t][2] * inv, ot[dt][t][3] * inv);
        unsigned short* p = Lq + (t2 * 16 + c) * 72 + dt * 16 + quad * 4;
        *(unsigned int*)(p) = w01;
        *(unsigned int*)(p + 2) = w23;
      }
    }
    // wave-local read-back (same wave wrote it; s_waitcnt handles ordering)
    const unsigned short* Lr = Lq + ql * 72 + hf * 32;
    unsigned short* Og = Ob + ((size_t)(b_ * SEQ + wq0 + half * 32 + ql)) * DM +
                         h_ * 64 + hf * 32;
#pragma unroll
    for (int j = 0; j < 4; ++j) {
      s16x8 v = *(const s16x8*)(Lr + j * 8);
      *(s16x8*)(Og + j * 8) = v;
    }
  }
}

// ---------------------------------------------------------------------------
extern "C" void kernel_launch(void* const* d_in, const int* in_sizes, int n_in,
                              void* d_out, int out_size, void* d_ws, size_t ws_size,
                              hipStream_t stream) {
  const float* q  = (const float*)d_in[0];
  const float* kv = (const float*)d_in[1];
  const float* Wq = (const float*)d_in[2];
  const float* bq = (const float*)d_in[3];
  const float* Wk = (const float*)d_in[4];
  const float* bk = (const float*)d_in[5];
  const float* Wv = (const float*)d_in[6];
  const float* bv = (const float*)d_in[7];
  const float* Wo = (const float*)d_in[8];
  const float* bo = (const float*)d_in[9];

  char* ws = (char*)d_ws;
  const size_t MB = 1024 * 1024;
  unsigned short* q_bf  = (unsigned short*)(ws);
  unsigned short* kv_bf = (unsigned short*)(ws + 16 * MB);
  unsigned short* wq_bf = (unsigned short*)(ws + 32 * MB);
  unsigned short* wk_bf = (unsigned short*)(ws + 34 * MB);
  unsigned short* wv_bf = (unsigned short*)(ws + 36 * MB);
  unsigned short* wo_bf = (unsigned short*)(ws + 38 * MB);
  unsigned short* Qb    = (unsigned short*)(ws + 40 * MB);
  unsigned short* Kb    = (unsigned short*)(ws + 56 * MB);
  unsigned short* VTb   = (unsigned short*)(ws + 72 * MB);
  unsigned short* attn  = (unsigned short*)(ws + 88 * MB);

  convert_all<<<2048, 256, 0, stream>>>(q, kv, Wq, Wk, Wv, Wo,
                                        q_bf, kv_bf, wq_bf, wk_bf, wv_bf, wo_bf);
  gemm_qkv<<<dim3(1536), 256, 0, stream>>>(q_bf, kv_bf, wq_bf, wk_bf, wv_bf,
                                           bq, bk, bv, Qb, Kb, VTb);
  attn_kernel<<<dim3(256), 512, 0, stream>>>(Qb, Kb, VTb, attn);
  gemm_o<<<dim3(512), 256, 0, stream>>>(attn, wo_bf, bo, (float*)d_out);
}

// Round 5
// 305.424 us; speedup vs baseline: 1.0665x; 1.0665x over previous
//
#include <hip/hip_runtime.h>

#define NH 16
#define DH 64
#define DM 1024
#define SEQ 2048
#define BATCH 4

typedef short s16x8 __attribute__((ext_vector_type(8)));
typedef float f32x4 __attribute__((ext_vector_type(4)));

__device__ __forceinline__ unsigned short f2bf(float f) {
  union { float f; unsigned int u; } v; v.f = f;
  unsigned int u = v.u;
  unsigned int r = (u + 0x7fffu + ((u >> 16) & 1u)) >> 16;
  return (unsigned short)r;
}

__device__ __forceinline__ unsigned int pkbf(float a, float b) {
#if __has_builtin(__builtin_amdgcn_cvt_pk_bf16_f32)
  typedef short v2s __attribute__((ext_vector_type(2)));
  v2s r = __builtin_amdgcn_cvt_pk_bf16_f32(a, b);
  union { v2s v; unsigned int u; } cv; cv.v = r;
  return cv.u;
#else
  return (unsigned int)f2bf(a) | ((unsigned int)f2bf(b) << 16);
#endif
}

__device__ __forceinline__ float fexp2(float x) {
#if __has_builtin(__builtin_amdgcn_exp2f)
  return __builtin_amdgcn_exp2f(x);
#else
  return exp2f(x);
#endif
}

__device__ __forceinline__ void gload_lds16(const void* g, void* l) {
  __builtin_amdgcn_global_load_lds(
      (const __attribute__((address_space(1))) unsigned int*)g,
      (__attribute__((address_space(3))) unsigned int*)l, 16, 0, 0);
}

// ---------------- fp32 -> bf16 convert (all tensors in one launch) ----------
__global__ void convert_all(const float* __restrict__ q, const float* __restrict__ kv,
                            const float* __restrict__ w0, const float* __restrict__ w1,
                            const float* __restrict__ w2, const float* __restrict__ w3,
                            unsigned short* __restrict__ oq, unsigned short* __restrict__ okv,
                            unsigned short* __restrict__ ow0, unsigned short* __restrict__ ow1,
                            unsigned short* __restrict__ ow2, unsigned short* __restrict__ ow3) {
  const int NQ4 = (BATCH * SEQ * DM) / 4;
  const int NW4 = (DM * DM) / 4;
  const int total = NQ4 * 2 + NW4 * 4;
  for (int i = blockIdx.x * blockDim.x + threadIdx.x; i < total;
       i += gridDim.x * blockDim.x) {
    const float* s; unsigned short* d; int off;
    if (i < NQ4)            { s = q;  d = oq;  off = i; }
    else if (i < 2 * NQ4)   { s = kv; d = okv; off = i - NQ4; }
    else {
      int j = i - 2 * NQ4; int wsel = j / NW4; off = j - wsel * NW4;
      s = (wsel == 0) ? w0 : (wsel == 1) ? w1 : (wsel == 2) ? w2 : w3;
      d = (wsel == 0) ? ow0 : (wsel == 1) ? ow1 : (wsel == 2) ? ow2 : ow3;
    }
    float4 v = *(const float4*)(s + (size_t)off * 4);
    ushort4 o;
    o.x = f2bf(v.x); o.y = f2bf(v.y); o.z = f2bf(v.z); o.w = f2bf(v.w);
    *(ushort4*)(d + (size_t)off * 4) = o;
  }
}

// ---------------- shared GEMM tile body (round-0 verified) ------------------
__device__ __forceinline__ void gemm_tile(const unsigned short* __restrict__ X,
                                          const unsigned short* __restrict__ Wt,
                                          unsigned short* As, unsigned short* Bs,
                                          int m0, int n0, f32x4 (*acc)[4]) {
  const int tid = threadIdx.x;
  const int wv_ = tid >> 6, lane = tid & 63;
  const int quad = lane >> 4, c = lane & 15;
  const int wm = (wv_ >> 1) * 64, wn = (wv_ & 1) * 64;
  const int srow = lane >> 3;
  const int scol = ((lane & 7) ^ srow) * 8;

  for (int kt = 0; kt < DM; kt += 64) {
#pragma unroll
    for (int i = 0; i < 4; ++i) {
      int reg = wv_ * 4 + i;
      gload_lds16(X + (size_t)(m0 + reg * 8 + srow) * DM + kt + scol,
                  (void*)(As + reg * 512));
      gload_lds16(Wt + (size_t)(n0 + reg * 8 + srow) * DM + kt + scol,
                  (void*)(Bs + reg * 512));
    }
    __syncthreads();
#pragma unroll
    for (int k2 = 0; k2 < 2; ++k2) {
      s16x8 a[4], b[4];
      int g = k2 * 4 + quad;
#pragma unroll
      for (int t = 0; t < 4; ++t)
        a[t] = *(const s16x8*)(As + (wm + t * 16 + c) * 64 + ((g ^ (c & 7)) * 8));
#pragma unroll
      for (int t = 0; t < 4; ++t)
        b[t] = *(const s16x8*)(Bs + (wn + t * 16 + c) * 64 + ((g ^ (c & 7)) * 8));
#pragma unroll
      for (int tm = 0; tm < 4; ++tm)
#pragma unroll
        for (int tn = 0; tn < 4; ++tn)
          acc[tm][tn] = __builtin_amdgcn_mfma_f32_16x16x32_bf16(
              a[tm], b[tn], acc[tm][tn], 0, 0, 0);
    }
    __syncthreads();
  }
}

// ---------------- fused QKV projection (round-3 config) ---------------------
__global__ __launch_bounds__(256)
void gemm_qkv(const unsigned short* __restrict__ Xq,
              const unsigned short* __restrict__ Xkv,
              const unsigned short* __restrict__ W0,
              const unsigned short* __restrict__ W1,
              const unsigned short* __restrict__ W2,
              const float* __restrict__ b0, const float* __restrict__ b1,
              const float* __restrict__ b2,
              unsigned short* __restrict__ OQ, unsigned short* __restrict__ OK_,
              unsigned short* __restrict__ OV) {
  __shared__ alignas(16) unsigned short As[128 * 64];
  __shared__ alignas(16) unsigned short Bs[128 * 64];
  const int m0 = blockIdx.x * 128;
  const int ysel = blockIdx.y >> 3;
  const int n0 = (blockIdx.y & 7) * 128;
  const unsigned short* X = (ysel == 0) ? Xq : Xkv;
  const unsigned short* Wt = (ysel == 0) ? W0 : (ysel == 1) ? W1 : W2;
  const float* bias = (ysel == 0) ? b0 : (ysel == 1) ? b1 : b2;
  unsigned short* Out = (ysel == 0) ? OQ : (ysel == 1) ? OK_ : OV;
  // Q pre-scaled by log2(e)/sqrt(Dh) so attention can use exp2 directly
  const float scale = (ysel == 0) ? 0.1803368801f : 1.0f;

  f32x4 acc[4][4] = {};
  gemm_tile(X, Wt, As, Bs, m0, n0, acc);

  const int tid = threadIdx.x;
  const int wv_ = tid >> 6, lane = tid & 63;
  const int quad = lane >> 4, c = lane & 15;
  const int wm = (wv_ >> 1) * 64, wn = (wv_ & 1) * 64;
#pragma unroll
  for (int tm = 0; tm < 4; ++tm) {
#pragma unroll
    for (int tn = 0; tn < 4; ++tn) {
      int n = n0 + wn + tn * 16 + c;
      float bv = bias[n];
      int m_base = m0 + wm + tm * 16 + quad * 4;
      if (ysel == 2) {
        // V^T: p -> consecutive s; one 8B store
        int b_ = m_base >> 11, s_ = m_base & 2047, h_ = n >> 6, dh = n & 63;
        size_t idx = (((size_t)(b_ * NH + h_)) * DH + dh) * SEQ + s_;
        ushort4 o4;
        o4.x = f2bf(acc[tm][tn][0] + bv);
        o4.y = f2bf(acc[tm][tn][1] + bv);
        o4.z = f2bf(acc[tm][tn][2] + bv);
        o4.w = f2bf(acc[tm][tn][3] + bv);
        *(ushort4*)(&Out[idx]) = o4;
      } else {
#pragma unroll
        for (int p = 0; p < 4; ++p) {
          int m = m_base + p;
          float val = (acc[tm][tn][p] + bv) * scale;
          int b_ = m >> 11, s_ = m & 2047, h_ = n >> 6, dh = n & 63;
          size_t idx = (((size_t)(b_ * NH + h_)) * SEQ + s_) * DH + dh;
          Out[idx] = f2bf(val);
        }
      }
    }
  }
}

// ---------------- output projection (fp32 out, round-3 config) -------------
__global__ __launch_bounds__(256)
void gemm_o(const unsigned short* __restrict__ X,
            const unsigned short* __restrict__ Wt,
            const float* __restrict__ bias, float* __restrict__ Out) {
  __shared__ alignas(16) unsigned short As[128 * 64];
  __shared__ alignas(16) unsigned short Bs[128 * 64];
  const int m0 = blockIdx.x * 128;
  const int n0 = blockIdx.y * 128;
  f32x4 acc[4][4] = {};
  gemm_tile(X, Wt, As, Bs, m0, n0, acc);

  const int tid = threadIdx.x;
  const int wv_ = tid >> 6, lane = tid & 63;
  const int quad = lane >> 4, c = lane & 15;
  const int wm = (wv_ >> 1) * 64, wn = (wv_ & 1) * 64;
#pragma unroll
  for (int tm = 0; tm < 4; ++tm) {
#pragma unroll
    for (int tn = 0; tn < 4; ++tn) {
      int n = n0 + wn + tn * 16 + c;
      float bv = bias[n];
#pragma unroll
      for (int p = 0; p < 4; ++p) {
        int m = m0 + wm + tm * 16 + quad * 4 + p;
        Out[(size_t)m * DM + n] = acc[tm][tn][p] + bv;
      }
    }
  }
}

// ---------------- flash attention v7 ---------------------------------------
// v6 + 2-way bank swizzle: stored chunk position = g ^ f(r),
//   f(r) = (r&3) | (((r>>3)&1)<<2)
// Old f(r)=r&7 made the K fragment read 4-way bank-conflicted (positions
// depended only on c&3 within a quad); new f separates (c&3, c>>2 parity)
// -> exactly 2 lanes per chunk column = free (m136). V read stays 2-way.
// Staging source pre-swizzle gains only a slab-parity bit.
__global__ __launch_bounds__(512, 2)
void attn_kernel(const unsigned short* __restrict__ Qb,
                 const unsigned short* __restrict__ Kb,
                 const unsigned short* __restrict__ VTb,
                 unsigned short* __restrict__ Ob) {
  __shared__ alignas(16) unsigned short SM[18432];   // 36 KB

  const int tid = threadIdx.x, wv_ = tid >> 6, lane = tid & 63;
  const int quad = lane >> 4, c = lane & 15;
  const int wg = blockIdx.x;                  // 0..255
  const int bh = (wg & 7) + 8 * ((wg >> 3) >> 2);   // XCD-chunked: bh%8 = XCD
  const int qb = (wg >> 3) & 3;
  const unsigned short* Qp = Qb + (size_t)bh * SEQ * DH;
  const unsigned short* Kp = Kb + (size_t)bh * SEQ * DH;
  const unsigned short* Vp = VTb + (size_t)bh * DH * SEQ;
  const int wq0 = qb * 512 + wv_ * 64;

  // Q fragments (B-operand: lane c = q column) live in registers
  s16x8 aq[4][2];
#pragma unroll
  for (int t = 0; t < 4; ++t)
#pragma unroll
    for (int k2 = 0; k2 < 2; ++k2)
      aq[t][k2] = *(const s16x8*)(Qp + (size_t)(wq0 + t * 16 + c) * DH +
                                  k2 * 32 + quad * 8);

  f32x4 ot[4][4] = {};     // O^T accum: [dh-tile][q-tile], lane c = q col
  f32x4 lacc[4] = {};      // row-sum accumulator via ones-MFMA
  s16x8 ones;
  {
    union { s16x8 v; unsigned short u[8]; } o_;
#pragma unroll
    for (int j = 0; j < 8; ++j) o_.u[j] = 0x3F80;   // bf16 1.0
    ones = o_.v;
  }

  const int srow = lane >> 3;                 // row within 8-row slab
  const int sbase = (lane & 7) ^ (srow & 3);  // source chunk sans slab parity

  // read-side swizzle offsets (chunk position = g ^ f)
  const int fK = (c & 3) | (((c >> 2) & 1) << 2);
  const int fV = (c & 3) | (((c >> 3) & 1) << 2);

  // prologue: stage tile 0 -> buffer 0. 16 slabs (8 K + 8 V), 2 per wave.
  // K buffers at shorts 0 / 4096; V at 8192 / 12288.
#pragma unroll
  for (int i = 0; i < 2; ++i) {
    int slab = wv_ * 2 + i;
    if (slab < 8) {
      int ch = sbase ^ ((slab & 1) << 2);
      gload_lds16(Kp + (size_t)(slab * 8 + srow) * DH + ch * 8,
                  (void*)(SM + slab * 512));
    } else {
      int s2 = slab - 8;
      int ch = sbase ^ ((s2 & 1) << 2);
      gload_lds16(Vp + (size_t)(s2 * 8 + srow) * SEQ + ch * 8,
                  (void*)(SM + 8192 + s2 * 512));
    }
  }

  for (int kt = 0; kt < SEQ; kt += 64) {
    const int cur = (kt >> 6) & 1;
    __syncthreads();   // drains this tile's loads; frees other buffer
    if (kt + 64 < SEQ) {
      const int nxt = cur ^ 1;
#pragma unroll
      for (int i = 0; i < 2; ++i) {
        int slab = wv_ * 2 + i;
        if (slab < 8) {
          int ch = sbase ^ ((slab & 1) << 2);
          gload_lds16(Kp + (size_t)(kt + 64 + slab * 8 + srow) * DH + ch * 8,
                      (void*)(SM + nxt * 4096 + slab * 512));
        } else {
          int s2 = slab - 8;
          int ch = sbase ^ ((s2 & 1) << 2);
          gload_lds16(Vp + (size_t)(s2 * 8 + srow) * SEQ + kt + 64 + ch * 8,
                      (void*)(SM + 8192 + nxt * 4096 + s2 * 512));
        }
      }
    }
    const unsigned short* K_ = SM + cur * 4096;
    const unsigned short* V_ = SM + 8192 + cur * 4096;

    // S^T tiles: rows = keys (permuted), cols = q.  s[t][jp][h] elem p holds
    // score(key = jp*32 + quad*8 + h*4 + p  [via row perm], q = wq0+t*16+c)
    f32x4 s[4][2][2] = {};
#pragma unroll
    for (int k2 = 0; k2 < 2; ++k2) {
      s16x8 ak[2][2];
#pragma unroll
      for (int jp = 0; jp < 2; ++jp)
#pragma unroll
        for (int h = 0; h < 2; ++h) {
          int r = jp * 32 + ((c >> 2) << 3) + h * 4 + (c & 3);  // key row perm
          int g = k2 * 4 + quad;
          ak[jp][h] = *(const s16x8*)(K_ + r * 64 + ((g ^ fK) * 8));
        }
#pragma unroll
      for (int t = 0; t < 4; ++t)
#pragma unroll
        for (int jp = 0; jp < 2; ++jp)
#pragma unroll
          for (int h = 0; h < 2; ++h)
            s[t][jp][h] = __builtin_amdgcn_mfma_f32_16x16x32_bf16(
                ak[jp][h], aq[t][k2], s[t][jp][h], 0, 0, 0);
    }

    // exp2 + in-register pack to PV B-fragments (k order quad*8+0..7)
    s16x8 bp[4][2];
#pragma unroll
    for (int t = 0; t < 4; ++t)
#pragma unroll
      for (int jp = 0; jp < 2; ++jp) {
        float e00 = fexp2(s[t][jp][0][0]);
        float e01 = fexp2(s[t][jp][0][1]);
        float e02 = fexp2(s[t][jp][0][2]);
        float e03 = fexp2(s[t][jp][0][3]);
        float e10 = fexp2(s[t][jp][1][0]);
        float e11 = fexp2(s[t][jp][1][1]);
        float e12 = fexp2(s[t][jp][1][2]);
        float e13 = fexp2(s[t][jp][1][3]);
        union { s16x8 v; unsigned int u[4]; } pk;
        pk.u[0] = pkbf(e00, e01);
        pk.u[1] = pkbf(e02, e03);
        pk.u[2] = pkbf(e10, e11);
        pk.u[3] = pkbf(e12, e13);
        bp[t][jp] = pk.v;
        // row sum on the matrix pipe: every lane's lacc[t][*] accumulates
        // the full 32-key column sum for its q column c.
        lacc[t] = __builtin_amdgcn_mfma_f32_16x16x32_bf16(
            ones, bp[t][jp], lacc[t], 0, 0, 0);
      }

    // O^T += V^T . P^T   (A = V^T rows: lane c = dh row; B = bp)
#pragma unroll
    for (int jp = 0; jp < 2; ++jp)
#pragma unroll
      for (int dt = 0; dt < 4; ++dt) {
        int g = jp * 4 + quad;
        int r = dt * 16 + c;
        s16x8 av = *(const s16x8*)(V_ + r * 64 + ((g ^ fV) * 8));
#pragma unroll
        for (int t = 0; t < 4; ++t)
          ot[dt][t] = __builtin_amdgcn_mfma_f32_16x16x32_bf16(
              av, bp[t][jp], ot[dt][t], 0, 0, 0);
      }
  }

  __syncthreads();   // all tile compute done; reuse SM for O transpose

  // O^T (lane=q col, regs=dh) -> LDS (q rows x dh cols, stride 72) -> global,
  // in two wave-local half-passes (q rows wq0+half*32 .. +31).
  const int b_ = bh >> 4, h_ = bh & 15;
  const int ql = lane >> 1, hf = lane & 1;
  unsigned short* Lq = SM + wv_ * (32 * 72);
#pragma unroll
  for (int half = 0; half < 2; ++half) {
    if (half) asm volatile("s_waitcnt lgkmcnt(0)" ::: "memory");  // pass-0 reads done
#pragma unroll
    for (int t2 = 0; t2 < 2; ++t2) {
      int t = half * 2 + t2;
      float inv = 1.0f / lacc[t][0];
#pragma unroll
      for (int dt = 0; dt < 4; ++dt) {
        unsigned int w01 = pkbf(ot[dt][t][0] * inv, ot[dt][t][1] * inv);
        unsigned int w23 = pkbf(ot[dt][t][2] * inv, ot[dt][t][3] * inv);
        unsigned short* p = Lq + (t2 * 16 + c) * 72 + dt * 16 + quad * 4;
        *(unsigned int*)(p) = w01;
        *(unsigned int*)(p + 2) = w23;
      }
    }
    // wave-local read-back (same wave wrote it; s_waitcnt handles ordering)
    const unsigned short* Lr = Lq + ql * 72 + hf * 32;
    unsigned short* Og = Ob + ((size_t)(b_ * SEQ + wq0 + half * 32 + ql)) * DM +
                         h_ * 64 + hf * 32;
#pragma unroll
    for (int j = 0; j < 4; ++j) {
      s16x8 v = *(const s16x8*)(Lr + j * 8);
      *(s16x8*)(Og + j * 8) = v;
    }
  }
}

// ---------------------------------------------------------------------------
extern "C" void kernel_launch(void* const* d_in, const int* in_sizes, int n_in,
                              void* d_out, int out_size, void* d_ws, size_t ws_size,
                              hipStream_t stream) {
  const float* q  = (const float*)d_in[0];
  const float* kv = (const float*)d_in[1];
  const float* Wq = (const float*)d_in[2];
  const float* bq = (const float*)d_in[3];
  const float* Wk = (const float*)d_in[4];
  const float* bk = (const float*)d_in[5];
  const float* Wv = (const float*)d_in[6];
  const float* bv = (const float*)d_in[7];
  const float* Wo = (const float*)d_in[8];
  const float* bo = (const float*)d_in[9];

  char* ws = (char*)d_ws;
  const size_t MB = 1024 * 1024;
  unsigned short* q_bf  = (unsigned short*)(ws);
  unsigned short* kv_bf = (unsigned short*)(ws + 16 * MB);
  unsigned short* wq_bf = (unsigned short*)(ws + 32 * MB);
  unsigned short* wk_bf = (unsigned short*)(ws + 34 * MB);
  unsigned short* wv_bf = (unsigned short*)(ws + 36 * MB);
  unsigned short* wo_bf = (unsigned short*)(ws + 38 * MB);
  unsigned short* Qb    = (unsigned short*)(ws + 40 * MB);
  unsigned short* Kb    = (unsigned short*)(ws + 56 * MB);
  unsigned short* VTb   = (unsigned short*)(ws + 72 * MB);
  unsigned short* attn  = (unsigned short*)(ws + 88 * MB);

  convert_all<<<2048, 256, 0, stream>>>(q, kv, Wq, Wk, Wv, Wo,
                                        q_bf, kv_bf, wq_bf, wk_bf, wv_bf, wo_bf);
  gemm_qkv<<<dim3(64, 24), 256, 0, stream>>>(q_bf, kv_bf, wq_bf, wk_bf, wv_bf,
                                             bq, bk, bv, Qb, Kb, VTb);
  attn_kernel<<<dim3(256), 512, 0, stream>>>(Qb, Kb, VTb, attn);
  gemm_o<<<dim3(64, 8), 256, 0, stream>>>(attn, wo_bf, bo, (float*)d_out);
}

// Round 6
// 304.859 us; speedup vs baseline: 1.0685x; 1.0019x over previous
//
#include <hip/hip_runtime.h>

#define NH 16
#define DH 64
#define DM 1024
#define SEQ 2048
#define BATCH 4

typedef short s16x8 __attribute__((ext_vector_type(8)));
typedef float f32x4 __attribute__((ext_vector_type(4)));

__device__ __forceinline__ unsigned short f2bf(float f) {
  union { float f; unsigned int u; } v; v.f = f;
  unsigned int u = v.u;
  unsigned int r = (u + 0x7fffu + ((u >> 16) & 1u)) >> 16;
  return (unsigned short)r;
}

__device__ __forceinline__ unsigned int pkbf(float a, float b) {
#if __has_builtin(__builtin_amdgcn_cvt_pk_bf16_f32)
  typedef short v2s __attribute__((ext_vector_type(2)));
  v2s r = __builtin_amdgcn_cvt_pk_bf16_f32(a, b);
  union { v2s v; unsigned int u; } cv; cv.v = r;
  return cv.u;
#else
  return (unsigned int)f2bf(a) | ((unsigned int)f2bf(b) << 16);
#endif
}

__device__ __forceinline__ float fexp2(float x) {
#if __has_builtin(__builtin_amdgcn_exp2f)
  return __builtin_amdgcn_exp2f(x);
#else
  return exp2f(x);
#endif
}

__device__ __forceinline__ void gload_lds16(const void* g, void* l) {
  __builtin_amdgcn_global_load_lds(
      (const __attribute__((address_space(1))) unsigned int*)g,
      (__attribute__((address_space(3))) unsigned int*)l, 16, 0, 0);
}

// ---------------- fp32 -> bf16 convert (all tensors in one launch) ----------
__global__ void convert_all(const float* __restrict__ q, const float* __restrict__ kv,
                            const float* __restrict__ w0, const float* __restrict__ w1,
                            const float* __restrict__ w2, const float* __restrict__ w3,
                            unsigned short* __restrict__ oq, unsigned short* __restrict__ okv,
                            unsigned short* __restrict__ ow0, unsigned short* __restrict__ ow1,
                            unsigned short* __restrict__ ow2, unsigned short* __restrict__ ow3) {
  const int NQ4 = (BATCH * SEQ * DM) / 4;
  const int NW4 = (DM * DM) / 4;
  const int total = NQ4 * 2 + NW4 * 4;
  for (int i = blockIdx.x * blockDim.x + threadIdx.x; i < total;
       i += gridDim.x * blockDim.x) {
    const float* s; unsigned short* d; int off;
    if (i < NQ4)            { s = q;  d = oq;  off = i; }
    else if (i < 2 * NQ4)   { s = kv; d = okv; off = i - NQ4; }
    else {
      int j = i - 2 * NQ4; int wsel = j / NW4; off = j - wsel * NW4;
      s = (wsel == 0) ? w0 : (wsel == 1) ? w1 : (wsel == 2) ? w2 : w3;
      d = (wsel == 0) ? ow0 : (wsel == 1) ? ow1 : (wsel == 2) ? ow2 : ow3;
    }
    float4 v = *(const float4*)(s + (size_t)off * 4);
    ushort4 o;
    o.x = f2bf(v.x); o.y = f2bf(v.y); o.z = f2bf(v.z); o.w = f2bf(v.w);
    *(ushort4*)(d + (size_t)off * 4) = o;
  }
}

// ---------------- shared GEMM tile body (round-0 verified) ------------------
__device__ __forceinline__ void gemm_tile(const unsigned short* __restrict__ X,
                                          const unsigned short* __restrict__ Wt,
                                          unsigned short* As, unsigned short* Bs,
                                          int m0, int n0, f32x4 (*acc)[4]) {
  const int tid = threadIdx.x;
  const int wv_ = tid >> 6, lane = tid & 63;
  const int quad = lane >> 4, c = lane & 15;
  const int wm = (wv_ >> 1) * 64, wn = (wv_ & 1) * 64;
  const int srow = lane >> 3;
  const int scol = ((lane & 7) ^ srow) * 8;

  for (int kt = 0; kt < DM; kt += 64) {
#pragma unroll
    for (int i = 0; i < 4; ++i) {
      int reg = wv_ * 4 + i;
      gload_lds16(X + (size_t)(m0 + reg * 8 + srow) * DM + kt + scol,
                  (void*)(As + reg * 512));
      gload_lds16(Wt + (size_t)(n0 + reg * 8 + srow) * DM + kt + scol,
                  (void*)(Bs + reg * 512));
    }
    __syncthreads();
#pragma unroll
    for (int k2 = 0; k2 < 2; ++k2) {
      s16x8 a[4], b[4];
      int g = k2 * 4 + quad;
#pragma unroll
      for (int t = 0; t < 4; ++t)
        a[t] = *(const s16x8*)(As + (wm + t * 16 + c) * 64 + ((g ^ (c & 7)) * 8));
#pragma unroll
      for (int t = 0; t < 4; ++t)
        b[t] = *(const s16x8*)(Bs + (wn + t * 16 + c) * 64 + ((g ^ (c & 7)) * 8));
#pragma unroll
      for (int tm = 0; tm < 4; ++tm)
#pragma unroll
        for (int tn = 0; tn < 4; ++tn)
          acc[tm][tn] = __builtin_amdgcn_mfma_f32_16x16x32_bf16(
              a[tm], b[tn], acc[tm][tn], 0, 0, 0);
    }
    __syncthreads();
  }
}

// ---------------- fused QKV projection (round-3 config) ---------------------
__global__ __launch_bounds__(256)
void gemm_qkv(const unsigned short* __restrict__ Xq,
              const unsigned short* __restrict__ Xkv,
              const unsigned short* __restrict__ W0,
              const unsigned short* __restrict__ W1,
              const unsigned short* __restrict__ W2,
              const float* __restrict__ b0, const float* __restrict__ b1,
              const float* __restrict__ b2,
              unsigned short* __restrict__ OQ, unsigned short* __restrict__ OK_,
              unsigned short* __restrict__ OV) {
  __shared__ alignas(16) unsigned short As[128 * 64];
  __shared__ alignas(16) unsigned short Bs[128 * 64];
  const int m0 = blockIdx.x * 128;
  const int ysel = blockIdx.y >> 3;
  const int n0 = (blockIdx.y & 7) * 128;
  const unsigned short* X = (ysel == 0) ? Xq : Xkv;
  const unsigned short* Wt = (ysel == 0) ? W0 : (ysel == 1) ? W1 : W2;
  const float* bias = (ysel == 0) ? b0 : (ysel == 1) ? b1 : b2;
  unsigned short* Out = (ysel == 0) ? OQ : (ysel == 1) ? OK_ : OV;
  // Q pre-scaled by log2(e)/sqrt(Dh) so attention can use exp2 directly
  const float scale = (ysel == 0) ? 0.1803368801f : 1.0f;

  f32x4 acc[4][4] = {};
  gemm_tile(X, Wt, As, Bs, m0, n0, acc);

  const int tid = threadIdx.x;
  const int wv_ = tid >> 6, lane = tid & 63;
  const int quad = lane >> 4, c = lane & 15;
  const int wm = (wv_ >> 1) * 64, wn = (wv_ & 1) * 64;
#pragma unroll
  for (int tm = 0; tm < 4; ++tm) {
#pragma unroll
    for (int tn = 0; tn < 4; ++tn) {
      int n = n0 + wn + tn * 16 + c;
      float bv = bias[n];
      int m_base = m0 + wm + tm * 16 + quad * 4;
      if (ysel == 2) {
        // V^T: p -> consecutive s; one 8B store
        int b_ = m_base >> 11, s_ = m_base & 2047, h_ = n >> 6, dh = n & 63;
        size_t idx = (((size_t)(b_ * NH + h_)) * DH + dh) * SEQ + s_;
        ushort4 o4;
        o4.x = f2bf(acc[tm][tn][0] + bv);
        o4.y = f2bf(acc[tm][tn][1] + bv);
        o4.z = f2bf(acc[tm][tn][2] + bv);
        o4.w = f2bf(acc[tm][tn][3] + bv);
        *(ushort4*)(&Out[idx]) = o4;
      } else {
#pragma unroll
        for (int p = 0; p < 4; ++p) {
          int m = m_base + p;
          float val = (acc[tm][tn][p] + bv) * scale;
          int b_ = m >> 11, s_ = m & 2047, h_ = n >> 6, dh = n & 63;
          size_t idx = (((size_t)(b_ * NH + h_)) * SEQ + s_) * DH + dh;
          Out[idx] = f2bf(val);
        }
      }
    }
  }
}

// ---------------- output projection (fp32 out, round-3 config) -------------
__global__ __launch_bounds__(256)
void gemm_o(const unsigned short* __restrict__ X,
            const unsigned short* __restrict__ Wt,
            const float* __restrict__ bias, float* __restrict__ Out) {
  __shared__ alignas(16) unsigned short As[128 * 64];
  __shared__ alignas(16) unsigned short Bs[128 * 64];
  const int m0 = blockIdx.x * 128;
  const int n0 = blockIdx.y * 128;
  f32x4 acc[4][4] = {};
  gemm_tile(X, Wt, As, Bs, m0, n0, acc);

  const int tid = threadIdx.x;
  const int wv_ = tid >> 6, lane = tid & 63;
  const int quad = lane >> 4, c = lane & 15;
  const int wm = (wv_ >> 1) * 64, wn = (wv_ & 1) * 64;
#pragma unroll
  for (int tm = 0; tm < 4; ++tm) {
#pragma unroll
    for (int tn = 0; tn < 4; ++tn) {
      int n = n0 + wn + tn * 16 + c;
      float bv = bias[n];
#pragma unroll
      for (int p = 0; p < 4; ++p) {
        int m = m0 + wm + tm * 16 + quad * 4 + p;
        Out[(size_t)m * DM + n] = acc[tm][tn][p] + bv;
      }
    }
  }
}

// ---------------- flash attention v8 ---------------------------------------
// v7 + KVBLK=128: one barrier per 128 keys (two 64-key compute halves) ->
// barrier/drain/refill events halve (32 -> 16); staging latency cover doubles.
// + T5 setprio(1/0) around QK and PV MFMA clusters (8 waves have role
// diversity between barriers -> scheduler can favor MFMA-entering waves).
// LDS 64KB: K at cur*8192 + kh*4096, V at 16384 + cur*8192 + kh*4096 (shorts).
// Swizzle identical to v7 (slab parity = wv_&1 on store == r>>3&1 on read).
__global__ __launch_bounds__(512, 2)
void attn_kernel(const unsigned short* __restrict__ Qb,
                 const unsigned short* __restrict__ Kb,
                 const unsigned short* __restrict__ VTb,
                 unsigned short* __restrict__ Ob) {
  __shared__ alignas(16) unsigned short SM[32768];   // 64 KB

  const int tid = threadIdx.x, wv_ = tid >> 6, lane = tid & 63;
  const int quad = lane >> 4, c = lane & 15;
  const int wg = blockIdx.x;                  // 0..255
  const int bh = (wg & 7) + 8 * ((wg >> 3) >> 2);   // XCD-chunked: bh%8 = XCD
  const int qb = (wg >> 3) & 3;
  const unsigned short* Qp = Qb + (size_t)bh * SEQ * DH;
  const unsigned short* Kp = Kb + (size_t)bh * SEQ * DH;
  const unsigned short* Vp = VTb + (size_t)bh * DH * SEQ;
  const int wq0 = qb * 512 + wv_ * 64;

  // Q fragments (B-operand: lane c = q column) live in registers
  s16x8 aq[4][2];
#pragma unroll
  for (int t = 0; t < 4; ++t)
#pragma unroll
    for (int k2 = 0; k2 < 2; ++k2)
      aq[t][k2] = *(const s16x8*)(Qp + (size_t)(wq0 + t * 16 + c) * DH +
                                  k2 * 32 + quad * 8);

  f32x4 ot[4][4] = {};     // O^T accum: [dh-tile][q-tile], lane c = q col
  f32x4 lacc[4] = {};      // row-sum accumulator via ones-MFMA
  s16x8 ones;
  {
    union { s16x8 v; unsigned short u[8]; } o_;
#pragma unroll
    for (int j = 0; j < 8; ++j) o_.u[j] = 0x3F80;   // bf16 1.0
    ones = o_.v;
  }

  const int srow = lane >> 3;                 // row within 8-row slab
  const int ch = ((lane & 7) ^ (srow & 3)) ^ ((wv_ & 1) << 2);  // src chunk

  // read-side swizzle offsets (chunk position = g ^ f)
  const int fK = (c & 3) | (((c >> 2) & 1) << 2);
  const int fV = (c & 3) | (((c >> 3) & 1) << 2);

  // stage one 128-key tile (4 gloads/wave): K halves + V halves, slab = wv_
#define STAGE_TILE(ktt, buf)                                                   \
  {                                                                            \
    gload_lds16(Kp + (size_t)((ktt) + wv_ * 8 + srow) * DH + ch * 8,           \
                (void*)(SM + (buf) * 8192 + wv_ * 512));                       \
    gload_lds16(Kp + (size_t)((ktt) + 64 + wv_ * 8 + srow) * DH + ch * 8,      \
                (void*)(SM + (buf) * 8192 + 4096 + wv_ * 512));                \
    gload_lds16(Vp + (size_t)(wv_ * 8 + srow) * SEQ + (ktt) + ch * 8,          \
                (void*)(SM + 16384 + (buf) * 8192 + wv_ * 512));               \
    gload_lds16(Vp + (size_t)(wv_ * 8 + srow) * SEQ + (ktt) + 64 + ch * 8,     \
                (void*)(SM + 16384 + (buf) * 8192 + 4096 + wv_ * 512));        \
  }

  STAGE_TILE(0, 0);

  for (int kt = 0; kt < SEQ; kt += 128) {
    const int cur = (kt >> 7) & 1;
    __syncthreads();   // drains this tile's loads; frees other buffer
    if (kt + 128 < SEQ) STAGE_TILE(kt + 128, cur ^ 1);

#pragma unroll
    for (int kh = 0; kh < 2; ++kh) {
      const unsigned short* K_ = SM + cur * 8192 + kh * 4096;
      const unsigned short* V_ = SM + 16384 + cur * 8192 + kh * 4096;

      // S^T tiles: rows = keys (permuted), cols = q.  s[t][jp][h] elem p holds
      // score(key = kh*64 + jp*32 + quad*8 + h*4 + p, q = wq0+t*16+c)
      f32x4 s[4][2][2] = {};
#pragma unroll
      for (int k2 = 0; k2 < 2; ++k2) {
        s16x8 ak[2][2];
#pragma unroll
        for (int jp = 0; jp < 2; ++jp)
#pragma unroll
          for (int h = 0; h < 2; ++h) {
            int r = jp * 32 + ((c >> 2) << 3) + h * 4 + (c & 3);  // key row perm
            int g = k2 * 4 + quad;
            ak[jp][h] = *(const s16x8*)(K_ + r * 64 + ((g ^ fK) * 8));
          }
        __builtin_amdgcn_s_setprio(1);
#pragma unroll
        for (int t = 0; t < 4; ++t)
#pragma unroll
          for (int jp = 0; jp < 2; ++jp)
#pragma unroll
            for (int h = 0; h < 2; ++h)
              s[t][jp][h] = __builtin_amdgcn_mfma_f32_16x16x32_bf16(
                  ak[jp][h], aq[t][k2], s[t][jp][h], 0, 0, 0);
        __builtin_amdgcn_s_setprio(0);
      }

      // exp2 + in-register pack to PV B-fragments (k order quad*8+0..7)
      s16x8 bp[4][2];
#pragma unroll
      for (int t = 0; t < 4; ++t)
#pragma unroll
        for (int jp = 0; jp < 2; ++jp) {
          float e00 = fexp2(s[t][jp][0][0]);
          float e01 = fexp2(s[t][jp][0][1]);
          float e02 = fexp2(s[t][jp][0][2]);
          float e03 = fexp2(s[t][jp][0][3]);
          float e10 = fexp2(s[t][jp][1][0]);
          float e11 = fexp2(s[t][jp][1][1]);
          float e12 = fexp2(s[t][jp][1][2]);
          float e13 = fexp2(s[t][jp][1][3]);
          union { s16x8 v; unsigned int u[4]; } pk;
          pk.u[0] = pkbf(e00, e01);
          pk.u[1] = pkbf(e02, e03);
          pk.u[2] = pkbf(e10, e11);
          pk.u[3] = pkbf(e12, e13);
          bp[t][jp] = pk.v;
          // row sum on the matrix pipe: every lane's lacc[t][*] accumulates
          // the full 32-key column sum for its q column c.
          lacc[t] = __builtin_amdgcn_mfma_f32_16x16x32_bf16(
              ones, bp[t][jp], lacc[t], 0, 0, 0);
        }

      // O^T += V^T . P^T   (A = V^T rows: lane c = dh row; B = bp)
#pragma unroll
      for (int jp = 0; jp < 2; ++jp)
#pragma unroll
        for (int dt = 0; dt < 4; ++dt) {
          int g = jp * 4 + quad;
          int r = dt * 16 + c;
          s16x8 av = *(const s16x8*)(V_ + r * 64 + ((g ^ fV) * 8));
          __builtin_amdgcn_s_setprio(1);
#pragma unroll
          for (int t = 0; t < 4; ++t)
            ot[dt][t] = __builtin_amdgcn_mfma_f32_16x16x32_bf16(
                av, bp[t][jp], ot[dt][t], 0, 0, 0);
          __builtin_amdgcn_s_setprio(0);
        }
    }
  }

  __syncthreads();   // all tile compute done; reuse SM for O transpose

  // O^T (lane=q col, regs=dh) -> LDS (q rows x dh cols, stride 72) -> global,
  // in two wave-local half-passes (q rows wq0+half*32 .. +31).
  const int b_ = bh >> 4, h_ = bh & 15;
  const int ql = lane >> 1, hf = lane & 1;
  unsigned short* Lq = SM + wv_ * (32 * 72);
#pragma unroll
  for (int half = 0; half < 2; ++half) {
    if (half) asm volatile("s_waitcnt lgkmcnt(0)" ::: "memory");  // pass-0 reads done
#pragma unroll
    for (int t2 = 0; t2 < 2; ++t2) {
      int t = half * 2 + t2;
      float inv = 1.0f / lacc[t][0];
#pragma unroll
      for (int dt = 0; dt < 4; ++dt) {
        unsigned int w01 = pkbf(ot[dt][t][0] * inv, ot[dt][t][1] * inv);
        unsigned int w23 = pkbf(ot[dt][t][2] * inv, ot[dt][t][3] * inv);
        unsigned short* p = Lq + (t2 * 16 + c) * 72 + dt * 16 + quad * 4;
        *(unsigned int*)(p) = w01;
        *(unsigned int*)(p + 2) = w23;
      }
    }
    // wave-local read-back (same wave wrote it; s_waitcnt handles ordering)
    const unsigned short* Lr = Lq + ql * 72 + hf * 32;
    unsigned short* Og = Ob + ((size_t)(b_ * SEQ + wq0 + half * 32 + ql)) * DM +
                         h_ * 64 + hf * 32;
#pragma unroll
    for (int j = 0; j < 4; ++j) {
      s16x8 v = *(const s16x8*)(Lr + j * 8);
      *(s16x8*)(Og + j * 8) = v;
    }
  }
#undef STAGE_TILE
}

// ---------------------------------------------------------------------------
extern "C" void kernel_launch(void* const* d_in, const int* in_sizes, int n_in,
                              void* d_out, int out_size, void* d_ws, size_t ws_size,
                              hipStream_t stream) {
  const float* q  = (const float*)d_in[0];
  const float* kv = (const float*)d_in[1];
  const float* Wq = (const float*)d_in[2];
  const float* bq = (const float*)d_in[3];
  const float* Wk = (const float*)d_in[4];
  const float* bk = (const float*)d_in[5];
  const float* Wv = (const float*)d_in[6];
  const float* bv = (const float*)d_in[7];
  const float* Wo = (const float*)d_in[8];
  const float* bo = (const float*)d_in[9];

  char* ws = (char*)d_ws;
  const size_t MB = 1024 * 1024;
  unsigned short* q_bf  = (unsigned short*)(ws);
  unsigned short* kv_bf = (unsigned short*)(ws + 16 * MB);
  unsigned short* wq_bf = (unsigned short*)(ws + 32 * MB);
  unsigned short* wk_bf = (unsigned short*)(ws + 34 * MB);
  unsigned short* wv_bf = (unsigned short*)(ws + 36 * MB);
  unsigned short* wo_bf = (unsigned short*)(ws + 38 * MB);
  unsigned short* Qb    = (unsigned short*)(ws + 40 * MB);
  unsigned short* Kb    = (unsigned short*)(ws + 56 * MB);
  unsigned short* VTb   = (unsigned short*)(ws + 72 * MB);
  unsigned short* attn  = (unsigned short*)(ws + 88 * MB);

  convert_all<<<2048, 256, 0, stream>>>(q, kv, Wq, Wk, Wv, Wo,
                                        q_bf, kv_bf, wq_bf, wk_bf, wv_bf, wo_bf);
  gemm_qkv<<<dim3(64, 24), 256, 0, stream>>>(q_bf, kv_bf, wq_bf, wk_bf, wv_bf,
                                             bq, bk, bv, Qb, Kb, VTb);
  attn_kernel<<<dim3(256), 512, 0, stream>>>(Qb, Kb, VTb, attn);
  gemm_o<<<dim3(64, 8), 256, 0, stream>>>(attn, wo_bf, bo, (float*)d_out);
}